// Round 1
// baseline (857.485 us; speedup 1.0000x reference)
//
#include <hip/hip_runtime.h>
#include <hip/hip_bf16.h>

using bf16 = __hip_bfloat16;
typedef __attribute__((ext_vector_type(8))) short short8;
typedef __attribute__((ext_vector_type(4))) float f32x4;
typedef __attribute__((ext_vector_type(4))) unsigned short us4;

static constexpr int Bn = 4, Sn = 2048, Dn = 1024;
static constexpr int ROWS = Bn * Sn;  // 8192
static constexpr float EPS = 1e-5f;

__device__ __forceinline__ void splitf(float v, bf16& hi, bf16& lo) {
    hi = __float2bfloat16(v);
    lo = __float2bfloat16(v - __bfloat162float(hi));
}

__device__ __forceinline__ void gload_lds16(const void* g, void* l) {
    __builtin_amdgcn_global_load_lds(
        (__attribute__((address_space(1))) void*)(void*)g,
        (__attribute__((address_space(3))) void*)l, 16, 0, 0);
}

// ---------- weight hi/lo split ----------
__global__ __launch_bounds__(256) void wsplit_kernel(const float* __restrict__ w,
                                                     bf16* __restrict__ hi,
                                                     bf16* __restrict__ lo, int n4) {
    int i = blockIdx.x * 256 + threadIdx.x;
    if (i >= n4) return;
    float4 v = reinterpret_cast<const float4*>(w)[i];
    int o = i * 4;
    bf16 h, l;
    splitf(v.x, h, l); hi[o+0] = h; lo[o+0] = l;
    splitf(v.y, h, l); hi[o+1] = h; lo[o+1] = l;
    splitf(v.z, h, l); hi[o+2] = h; lo[o+2] = l;
    splitf(v.w, h, l); hi[o+3] = h; lo[o+3] = l;
}

// ---------- LayerNorm -> h (hi/lo bf16) ----------
__global__ __launch_bounds__(256) void ln_kernel(const float* __restrict__ x,
                                                 const float* __restrict__ w,
                                                 bf16* __restrict__ hhi,
                                                 bf16* __restrict__ hlo) {
    const int row = blockIdx.x, tid = threadIdx.x;
    const int lane = tid & 63, wave = tid >> 6;
    const float4 v = reinterpret_cast<const float4*>(x + (size_t)row * Dn)[tid];
    float s  = v.x + v.y + v.z + v.w;
    float s2 = v.x*v.x + v.y*v.y + v.z*v.z + v.w*v.w;
    #pragma unroll
    for (int off = 32; off > 0; off >>= 1) {
        s  += __shfl_down(s,  off, 64);
        s2 += __shfl_down(s2, off, 64);
    }
    __shared__ float red[8];
    if (lane == 0) { red[wave] = s; red[4 + wave] = s2; }
    __syncthreads();
    s  = red[0] + red[1] + red[2] + red[3];
    s2 = red[4] + red[5] + red[6] + red[7];
    const float mu  = s * (1.0f / Dn);
    const float var = s2 * (1.0f / Dn) - mu * mu;
    const float rs  = rsqrtf(var + EPS);
    const float4 wv = reinterpret_cast<const float4*>(w)[tid];
    const size_t o = (size_t)row * Dn + tid * 4;
    bf16 h, l;
    splitf((v.x - mu) * rs * wv.x, h, l); hhi[o+0] = h; hlo[o+0] = l;
    splitf((v.y - mu) * rs * wv.y, h, l); hhi[o+1] = h; hlo[o+1] = l;
    splitf((v.z - mu) * rs * wv.z, h, l); hhi[o+2] = h; hlo[o+2] = l;
    splitf((v.w - mu) * rs * wv.w, h, l); hhi[o+3] = h; hlo[o+3] = l;
}

// ---------- row softmax (2048 wide), writes bf16 hi/lo in place ----------
__global__ __launch_bounds__(256) void softmax_kernel(float* __restrict__ scores) {
    const int row = blockIdx.x, tid = threadIdx.x;
    const int lane = tid & 63, wave = tid >> 6;
    float* r = scores + (size_t)row * Sn;
    const float4 v0 = reinterpret_cast<const float4*>(r)[tid];
    const float4 v1 = reinterpret_cast<const float4*>(r)[tid + 256];
    float m = fmaxf(fmaxf(fmaxf(v0.x, v0.y), fmaxf(v0.z, v0.w)),
                    fmaxf(fmaxf(v1.x, v1.y), fmaxf(v1.z, v1.w)));
    #pragma unroll
    for (int off = 32; off > 0; off >>= 1) m = fmaxf(m, __shfl_down(m, off, 64));
    __shared__ float red[8];
    if (lane == 0) red[wave] = m;
    __syncthreads();
    m = fmaxf(fmaxf(red[0], red[1]), fmaxf(red[2], red[3]));
    float e[8];
    e[0] = expf(v0.x - m); e[1] = expf(v0.y - m);
    e[2] = expf(v0.z - m); e[3] = expf(v0.w - m);
    e[4] = expf(v1.x - m); e[5] = expf(v1.y - m);
    e[6] = expf(v1.z - m); e[7] = expf(v1.w - m);
    float s = e[0]+e[1]+e[2]+e[3]+e[4]+e[5]+e[6]+e[7];
    #pragma unroll
    for (int off = 32; off > 0; off >>= 1) s += __shfl_down(s, off, 64);
    if (lane == 0) red[4 + wave] = s;
    __syncthreads();
    s = red[4] + red[5] + red[6] + red[7];
    const float inv = 1.0f / s;
    // in-place: this row's 8 KB becomes [2048 bf16 hi | 2048 bf16 lo]
    bf16* hi = reinterpret_cast<bf16*>(r);
    bf16* lo = hi + Sn;
    bf16 h, l;
    #pragma unroll
    for (int j = 0; j < 4; ++j) {
        splitf(e[j] * inv, h, l);
        hi[tid*4 + j] = h; lo[tid*4 + j] = l;
    }
    #pragma unroll
    for (int j = 0; j < 4; ++j) {
        splitf(e[4+j] * inv, h, l);
        hi[1024 + tid*4 + j] = h; lo[1024 + tid*4 + j] = l;
    }
}

// ---------- split-3 MFMA GEMM: C = (Ahi+Alo) @ (Bhi+Blo)^T ----------
// SM: 0 = store f32, 1 = store bf16 hi/lo, 2 = store bf16 hi/lo transposed
template <int SM>
__global__ __launch_bounds__(256)
void gemm3(const bf16* __restrict__ Ahi, const bf16* __restrict__ Alo, int lda, long long sA,
           const bf16* __restrict__ Bhi, const bf16* __restrict__ Blo, int ldb, long long sB,
           float* __restrict__ Cf, bf16* __restrict__ Chi, bf16* __restrict__ Clo,
           int ldc, long long sC, int K) {
    const int tid = threadIdx.x;
    const int lane = tid & 63, wave = tid >> 6;
    const int bm = blockIdx.x, bn = blockIdx.y;
    const long long aBase = (long long)blockIdx.z * sA;
    const long long bBase = (long long)blockIdx.z * sB;
    const long long cBase = (long long)blockIdx.z * sC;

    __shared__ bf16 sAh[128*32], sAl[128*32], sBh[128*32], sBl[128*32];

    f32x4 acc[4][4];
    #pragma unroll
    for (int i = 0; i < 4; ++i)
        #pragma unroll
        for (int j = 0; j < 4; ++j) acc[i][j] = f32x4{0.f, 0.f, 0.f, 0.f};

    const int wm = wave >> 1, wn = wave & 1;
    const int fr = lane & 15;
    const int kb = (lane >> 4) * 8;

    for (int k0 = 0; k0 < K; k0 += 32) {
        #pragma unroll
        for (int i = 0; i < 2; ++i) {
            const int idx = (i * 4 + wave) * 64 + lane;
            const int row = idx >> 2;
            const int seg = (idx & 3) * 8;
            const int lds_off = (i * 4 + wave) * 512;  // wave-uniform
            const long long ga = aBase + (long long)(bm * 128 + row) * lda + k0 + seg;
            const long long gb = bBase + (long long)(bn * 128 + row) * ldb + k0 + seg;
            gload_lds16(Ahi + ga, sAh + lds_off);
            gload_lds16(Alo + ga, sAl + lds_off);
            gload_lds16(Bhi + gb, sBh + lds_off);
            gload_lds16(Blo + gb, sBl + lds_off);
        }
        __syncthreads();

        short8 ah[4], al[4], bh[4], bl[4];
        #pragma unroll
        for (int t = 0; t < 4; ++t) {
            ah[t] = *reinterpret_cast<const short8*>(sAh + (wm*64 + t*16 + fr) * 32 + kb);
            al[t] = *reinterpret_cast<const short8*>(sAl + (wm*64 + t*16 + fr) * 32 + kb);
            bh[t] = *reinterpret_cast<const short8*>(sBh + (wn*64 + t*16 + fr) * 32 + kb);
            bl[t] = *reinterpret_cast<const short8*>(sBl + (wn*64 + t*16 + fr) * 32 + kb);
        }
        #pragma unroll
        for (int mi = 0; mi < 4; ++mi)
            #pragma unroll
            for (int ni = 0; ni < 4; ++ni) {
                acc[mi][ni] = __builtin_amdgcn_mfma_f32_16x16x32_bf16(ah[mi], bh[ni], acc[mi][ni], 0, 0, 0);
                acc[mi][ni] = __builtin_amdgcn_mfma_f32_16x16x32_bf16(ah[mi], bl[ni], acc[mi][ni], 0, 0, 0);
                acc[mi][ni] = __builtin_amdgcn_mfma_f32_16x16x32_bf16(al[mi], bh[ni], acc[mi][ni], 0, 0, 0);
            }
        __syncthreads();
    }

    #pragma unroll
    for (int mi = 0; mi < 4; ++mi) {
        const int row0 = bm * 128 + wm * 64 + mi * 16 + (lane >> 4) * 4;
        #pragma unroll
        for (int ni = 0; ni < 4; ++ni) {
            const int col = bn * 128 + wn * 64 + ni * 16 + fr;
            if constexpr (SM == 0) {
                #pragma unroll
                for (int r = 0; r < 4; ++r)
                    Cf[cBase + (long long)(row0 + r) * ldc + col] = acc[mi][ni][r];
            } else if constexpr (SM == 1) {
                #pragma unroll
                for (int r = 0; r < 4; ++r) {
                    bf16 h, l; splitf(acc[mi][ni][r], h, l);
                    const long long o = cBase + (long long)(row0 + r) * ldc + col;
                    Chi[o] = h; Clo[o] = l;
                }
            } else {
                alignas(8) bf16 th[4], tl[4];
                #pragma unroll
                for (int r = 0; r < 4; ++r) splitf(acc[mi][ni][r], th[r], tl[r]);
                const long long o = cBase + (long long)col * ldc + row0;
                *reinterpret_cast<us4*>(Chi + o) = *reinterpret_cast<const us4*>(th);
                *reinterpret_cast<us4*>(Clo + o) = *reinterpret_cast<const us4*>(tl);
            }
        }
    }
}

extern "C" void kernel_launch(void* const* d_in, const int* in_sizes, int n_in,
                              void* d_out, int out_size, void* d_ws, size_t ws_size,
                              hipStream_t stream) {
    const float* x    = (const float*)d_in[0];
    const float* ln_w = (const float*)d_in[1];
    const float* wq   = (const float*)d_in[2];
    const float* wk   = (const float*)d_in[3];
    const float* wv   = (const float*)d_in[4];
    const float* wo   = (const float*)d_in[5];
    float* out = (float*)d_out;

    const size_t WSZ = (size_t)Dn * Dn;    // 1M elements (2 MiB as bf16)
    const size_t HSZ = (size_t)ROWS * Dn;  // 8M elements (16 MiB as bf16)
    bf16* base  = (bf16*)d_ws;             // total ws use: 176 MiB
    bf16* wq_hi = base;          bf16* wq_lo = wq_hi + WSZ;
    bf16* wk_hi = wq_lo + WSZ;   bf16* wk_lo = wk_hi + WSZ;
    bf16* wv_hi = wk_lo + WSZ;   bf16* wv_lo = wv_hi + WSZ;
    bf16* wo_hi = wv_lo + WSZ;   bf16* wo_lo = wo_hi + WSZ;
    bf16* h_hi  = wo_lo + WSZ;   bf16* h_lo  = h_hi + HSZ;
    bf16* q_hi  = h_lo + HSZ;    bf16* q_lo  = q_hi + HSZ;
    bf16* k_hi  = q_lo + HSZ;    bf16* k_lo  = k_hi + HSZ;
    bf16* vt_hi = k_lo + HSZ;    bf16* vt_lo = vt_hi + HSZ;
    bf16* ctx_hi= vt_lo + HSZ;   bf16* ctx_lo= ctx_hi + HSZ;
    float* scores = out;  // d_out (32 MiB) as scratch; fully overwritten at the end

    // 1. weight splits
    const int n4 = (int)(WSZ / 4);
    wsplit_kernel<<<dim3((n4 + 255) / 256), 256, 0, stream>>>(wq, wq_hi, wq_lo, n4);
    wsplit_kernel<<<dim3((n4 + 255) / 256), 256, 0, stream>>>(wk, wk_hi, wk_lo, n4);
    wsplit_kernel<<<dim3((n4 + 255) / 256), 256, 0, stream>>>(wv, wv_hi, wv_lo, n4);
    wsplit_kernel<<<dim3((n4 + 255) / 256), 256, 0, stream>>>(wo, wo_hi, wo_lo, n4);

    // 2. LayerNorm + split
    ln_kernel<<<ROWS, 256, 0, stream>>>(x, ln_w, h_hi, h_lo);

    // 3. Q = h @ wq^T, K = h @ wk^T  (store hi/lo)
    gemm3<1><<<dim3(ROWS/128, Dn/128), 256, 0, stream>>>(
        h_hi, h_lo, Dn, 0, wq_hi, wq_lo, Dn, 0,
        nullptr, q_hi, q_lo, Dn, 0, Dn);
    gemm3<1><<<dim3(ROWS/128, Dn/128), 256, 0, stream>>>(
        h_hi, h_lo, Dn, 0, wk_hi, wk_lo, Dn, 0,
        nullptr, k_hi, k_lo, Dn, 0, Dn);

    // 4. V = h @ wv^T, stored transposed per batch: vt[b][d][s]
    gemm3<2><<<dim3(Sn/128, Dn/128, Bn), 256, 0, stream>>>(
        h_hi, h_lo, Dn, (long long)Sn * Dn, wv_hi, wv_lo, Dn, 0,
        nullptr, vt_hi, vt_lo, Sn, (long long)Dn * Sn, Dn);

    // 5. attention, one batch at a time (scores buffer reused)
    for (int b = 0; b < Bn; ++b) {
        const size_t qoff = (size_t)b * Sn * Dn;
        // scores = q @ k^T  (f32)
        gemm3<0><<<dim3(Sn/128, Sn/128), 256, 0, stream>>>(
            q_hi + qoff, q_lo + qoff, Dn, 0, k_hi + qoff, k_lo + qoff, Dn, 0,
            scores, nullptr, nullptr, Sn, 0, Dn);
        // softmax rows -> bf16 hi/lo in place (row-local, stride 4096 bf16)
        softmax_kernel<<<Sn, 256, 0, stream>>>(scores);
        // ctx = attn @ v  (A = attn hi/lo, B = vt[b])
        gemm3<1><<<dim3(Sn/128, Dn/128), 256, 0, stream>>>(
            (const bf16*)scores, (const bf16*)scores + Sn, 2 * Sn, 0,
            vt_hi + (size_t)b * Dn * Sn, vt_lo + (size_t)b * Dn * Sn, Sn, 0,
            nullptr, ctx_hi + qoff, ctx_lo + qoff, Dn, 0, Sn);
    }

    // 6. out = ctx @ wo^T  (f32 -> d_out)
    gemm3<0><<<dim3(ROWS/128, Dn/128), 256, 0, stream>>>(
        ctx_hi, ctx_lo, Dn, 0, wo_hi, wo_lo, Dn, 0,
        out, nullptr, nullptr, Dn, 0, Dn);
}

// Round 2
// 473.652 us; speedup vs baseline: 1.8104x; 1.8104x over previous
//
#include <hip/hip_runtime.h>
#include <hip/hip_bf16.h>

using bf16 = __hip_bfloat16;
typedef __attribute__((ext_vector_type(8))) short short8;
typedef __attribute__((ext_vector_type(4))) float f32x4;
typedef __attribute__((ext_vector_type(4))) unsigned short us4;

static constexpr int Bn = 4, Sn = 2048, Dn = 1024;
static constexpr int ROWS = Bn * Sn;  // 8192
static constexpr float EPS = 1e-5f;

__device__ __forceinline__ void splitf(float v, bf16& hi, bf16& lo) {
    hi = __float2bfloat16(v);
    lo = __float2bfloat16(v - __bfloat162float(hi));
}

__device__ __forceinline__ void gload_lds16(const void* g, void* l) {
    __builtin_amdgcn_global_load_lds(
        (__attribute__((address_space(1))) void*)(void*)g,
        (__attribute__((address_space(3))) void*)l, 16, 0, 0);
}

// ---------- weight hi/lo split ----------
template <bool LO>
__global__ __launch_bounds__(256) void wsplit_kernel(const float* __restrict__ w,
                                                     bf16* __restrict__ hi,
                                                     bf16* __restrict__ lo, int n4) {
    int i = blockIdx.x * 256 + threadIdx.x;
    if (i >= n4) return;
    float4 v = reinterpret_cast<const float4*>(w)[i];
    int o = i * 4;
    bf16 h, l;
    splitf(v.x, h, l); hi[o+0] = h; if constexpr (LO) lo[o+0] = l;
    splitf(v.y, h, l); hi[o+1] = h; if constexpr (LO) lo[o+1] = l;
    splitf(v.z, h, l); hi[o+2] = h; if constexpr (LO) lo[o+2] = l;
    splitf(v.w, h, l); hi[o+3] = h; if constexpr (LO) lo[o+3] = l;
}

// ---------- LayerNorm -> h (hi/lo bf16) ----------
__global__ __launch_bounds__(256) void ln_kernel(const float* __restrict__ x,
                                                 const float* __restrict__ w,
                                                 bf16* __restrict__ hhi,
                                                 bf16* __restrict__ hlo) {
    const int row = blockIdx.x, tid = threadIdx.x;
    const int lane = tid & 63, wave = tid >> 6;
    const float4 v = reinterpret_cast<const float4*>(x + (size_t)row * Dn)[tid];
    float s  = v.x + v.y + v.z + v.w;
    float s2 = v.x*v.x + v.y*v.y + v.z*v.z + v.w*v.w;
    #pragma unroll
    for (int off = 32; off > 0; off >>= 1) {
        s  += __shfl_down(s,  off, 64);
        s2 += __shfl_down(s2, off, 64);
    }
    __shared__ float red[8];
    if (lane == 0) { red[wave] = s; red[4 + wave] = s2; }
    __syncthreads();
    s  = red[0] + red[1] + red[2] + red[3];
    s2 = red[4] + red[5] + red[6] + red[7];
    const float mu  = s * (1.0f / Dn);
    const float var = s2 * (1.0f / Dn) - mu * mu;
    const float rs  = rsqrtf(var + EPS);
    const float4 wv = reinterpret_cast<const float4*>(w)[tid];
    const size_t o = (size_t)row * Dn + tid * 4;
    bf16 h, l;
    splitf((v.x - mu) * rs * wv.x, h, l); hhi[o+0] = h; hlo[o+0] = l;
    splitf((v.y - mu) * rs * wv.y, h, l); hhi[o+1] = h; hlo[o+1] = l;
    splitf((v.z - mu) * rs * wv.z, h, l); hhi[o+2] = h; hlo[o+2] = l;
    splitf((v.w - mu) * rs * wv.w, h, l); hhi[o+3] = h; hlo[o+3] = l;
}

// ---------- row softmax (2048 wide), writes plain bf16 P in place ----------
__global__ __launch_bounds__(256) void softmax_kernel(float* __restrict__ scores) {
    const int row = blockIdx.x, tid = threadIdx.x;
    const int lane = tid & 63, wave = tid >> 6;
    float* r = scores + (size_t)row * Sn;
    const float4 v0 = reinterpret_cast<const float4*>(r)[tid];
    const float4 v1 = reinterpret_cast<const float4*>(r)[tid + 256];
    float m = fmaxf(fmaxf(fmaxf(v0.x, v0.y), fmaxf(v0.z, v0.w)),
                    fmaxf(fmaxf(v1.x, v1.y), fmaxf(v1.z, v1.w)));
    #pragma unroll
    for (int off = 32; off > 0; off >>= 1) m = fmaxf(m, __shfl_down(m, off, 64));
    __shared__ float red[8];
    if (lane == 0) red[wave] = m;
    __syncthreads();
    m = fmaxf(fmaxf(red[0], red[1]), fmaxf(red[2], red[3]));
    float e[8];
    e[0] = expf(v0.x - m); e[1] = expf(v0.y - m);
    e[2] = expf(v0.z - m); e[3] = expf(v0.w - m);
    e[4] = expf(v1.x - m); e[5] = expf(v1.y - m);
    e[6] = expf(v1.z - m); e[7] = expf(v1.w - m);
    float s = e[0]+e[1]+e[2]+e[3]+e[4]+e[5]+e[6]+e[7];
    #pragma unroll
    for (int off = 32; off > 0; off >>= 1) s += __shfl_down(s, off, 64);
    if (lane == 0) red[4 + wave] = s;
    __syncthreads();
    s = red[4] + red[5] + red[6] + red[7];
    const float inv = 1.0f / s;
    // in-place: row's first 4 KB becomes 2048 bf16 probabilities
    bf16* hi = reinterpret_cast<bf16*>(r);
    #pragma unroll
    for (int j = 0; j < 4; ++j) hi[tid*4 + j]        = __float2bfloat16(e[j] * inv);
    #pragma unroll
    for (int j = 0; j < 4; ++j) hi[1024 + tid*4 + j] = __float2bfloat16(e[4+j] * inv);
}

// ---------- MFMA GEMM: C = A @ B^T ----------
// NT: 3 = (Ah*Bh + Ah*Bl + Al*Bh) split-3; 1 = Ah*Bh only
// SM: 0 = f32 store, 1 = bf16 hi/lo split store, 2 = bf16 hi transposed, 3 = bf16 hi
template <int NT, int SM>
__global__ __launch_bounds__(256)
void gemm3(const bf16* __restrict__ Ahi, const bf16* __restrict__ Alo, int lda, long long sA,
           const bf16* __restrict__ Bhi, const bf16* __restrict__ Blo, int ldb, long long sB,
           float* __restrict__ Cf, bf16* __restrict__ Chi, bf16* __restrict__ Clo,
           int ldc, long long sC, int K) {
    const int tid = threadIdx.x;
    const int lane = tid & 63, wave = tid >> 6;
    const int bm = blockIdx.x, bn = blockIdx.y;
    const long long aBase = (long long)blockIdx.z * sA;
    const long long bBase = (long long)blockIdx.z * sB;
    const long long cBase = (long long)blockIdx.z * sC;

    __shared__ bf16 sAh[128*32];
    __shared__ bf16 sBh[128*32];
    __shared__ bf16 sAl[NT == 3 ? 128*32 : 64];
    __shared__ bf16 sBl[NT == 3 ? 128*32 : 64];

    f32x4 acc[4][4];
    #pragma unroll
    for (int i = 0; i < 4; ++i)
        #pragma unroll
        for (int j = 0; j < 4; ++j) acc[i][j] = f32x4{0.f, 0.f, 0.f, 0.f};

    const int wm = wave >> 1, wn = wave & 1;
    const int fr = lane & 15;
    const int kb = (lane >> 4) * 8;

    for (int k0 = 0; k0 < K; k0 += 32) {
        #pragma unroll
        for (int i = 0; i < 2; ++i) {
            const int idx = (i * 4 + wave) * 64 + lane;
            const int row = idx >> 2;
            const int seg = (idx & 3) * 8;
            const int lds_off = (i * 4 + wave) * 512;  // wave-uniform
            const long long ga = aBase + (long long)(bm * 128 + row) * lda + k0 + seg;
            const long long gb = bBase + (long long)(bn * 128 + row) * ldb + k0 + seg;
            gload_lds16(Ahi + ga, sAh + lds_off);
            gload_lds16(Bhi + gb, sBh + lds_off);
            if constexpr (NT == 3) {
                gload_lds16(Alo + ga, sAl + lds_off);
                gload_lds16(Blo + gb, sBl + lds_off);
            }
        }
        __syncthreads();

        short8 ah[4], bh[4];
        #pragma unroll
        for (int t = 0; t < 4; ++t) {
            ah[t] = *reinterpret_cast<const short8*>(sAh + (wm*64 + t*16 + fr) * 32 + kb);
            bh[t] = *reinterpret_cast<const short8*>(sBh + (wn*64 + t*16 + fr) * 32 + kb);
        }
        if constexpr (NT == 3) {
            short8 al[4], bl[4];
            #pragma unroll
            for (int t = 0; t < 4; ++t) {
                al[t] = *reinterpret_cast<const short8*>(sAl + (wm*64 + t*16 + fr) * 32 + kb);
                bl[t] = *reinterpret_cast<const short8*>(sBl + (wn*64 + t*16 + fr) * 32 + kb);
            }
            #pragma unroll
            for (int mi = 0; mi < 4; ++mi)
                #pragma unroll
                for (int ni = 0; ni < 4; ++ni) {
                    acc[mi][ni] = __builtin_amdgcn_mfma_f32_16x16x32_bf16(ah[mi], bh[ni], acc[mi][ni], 0, 0, 0);
                    acc[mi][ni] = __builtin_amdgcn_mfma_f32_16x16x32_bf16(ah[mi], bl[ni], acc[mi][ni], 0, 0, 0);
                    acc[mi][ni] = __builtin_amdgcn_mfma_f32_16x16x32_bf16(al[mi], bh[ni], acc[mi][ni], 0, 0, 0);
                }
        } else {
            #pragma unroll
            for (int mi = 0; mi < 4; ++mi)
                #pragma unroll
                for (int ni = 0; ni < 4; ++ni)
                    acc[mi][ni] = __builtin_amdgcn_mfma_f32_16x16x32_bf16(ah[mi], bh[ni], acc[mi][ni], 0, 0, 0);
        }
        __syncthreads();
    }

    #pragma unroll
    for (int mi = 0; mi < 4; ++mi) {
        const int row0 = bm * 128 + wm * 64 + mi * 16 + (lane >> 4) * 4;
        #pragma unroll
        for (int ni = 0; ni < 4; ++ni) {
            const int col = bn * 128 + wn * 64 + ni * 16 + fr;
            if constexpr (SM == 0) {
                #pragma unroll
                for (int r = 0; r < 4; ++r)
                    Cf[cBase + (long long)(row0 + r) * ldc + col] = acc[mi][ni][r];
            } else if constexpr (SM == 1) {
                #pragma unroll
                for (int r = 0; r < 4; ++r) {
                    bf16 h, l; splitf(acc[mi][ni][r], h, l);
                    const long long o = cBase + (long long)(row0 + r) * ldc + col;
                    Chi[o] = h; Clo[o] = l;
                }
            } else if constexpr (SM == 2) {
                alignas(8) bf16 th[4];
                #pragma unroll
                for (int r = 0; r < 4; ++r) th[r] = __float2bfloat16(acc[mi][ni][r]);
                const long long o = cBase + (long long)col * ldc + row0;
                *reinterpret_cast<us4*>(Chi + o) = *reinterpret_cast<const us4*>(th);
            } else {
                #pragma unroll
                for (int r = 0; r < 4; ++r)
                    Chi[cBase + (long long)(row0 + r) * ldc + col] = __float2bfloat16(acc[mi][ni][r]);
            }
        }
    }
}

extern "C" void kernel_launch(void* const* d_in, const int* in_sizes, int n_in,
                              void* d_out, int out_size, void* d_ws, size_t ws_size,
                              hipStream_t stream) {
    const float* x    = (const float*)d_in[0];
    const float* ln_w = (const float*)d_in[1];
    const float* wq   = (const float*)d_in[2];
    const float* wk   = (const float*)d_in[3];
    const float* wv   = (const float*)d_in[4];
    const float* wo   = (const float*)d_in[5];
    float* out = (float*)d_out;

    const size_t M1 = 1u << 20;
    bf16* base = (bf16*)d_ws;
    // transient region [0, 64 MB) — dead after the V GEMM, then reused as f32 scores
    bf16* h_hi   = base;             // 8M elems
    bf16* h_lo   = base + 8*M1;      // 8M
    bf16* wqk_hi = base + 16*M1;     // 2M (wq rows 0..1023, wk rows 1024..2047)
    bf16* wqk_lo = base + 18*M1;     // 2M
    bf16* wv_hi  = base + 20*M1;     // 1M
    // persistent region [64 MB, 162 MB)
    bf16* qk_hi  = base + 32*M1;     // 16M: [8192][2048], q cols 0..1023, k cols 1024..2047
    bf16* qk_lo  = base + 48*M1;     // 16M
    bf16* vt     = base + 64*M1;     // 8M: [4][1024][2048]
    bf16* ctx    = base + 72*M1;     // 8M: [8192][1024]
    bf16* wo_hi  = base + 80*M1;     // 1M
    float* scores = (float*)base;    // 16M f32 = 64 MB, overlays transient region

    // 1. weight splits
    const int n4 = (int)(M1 / 4);
    wsplit_kernel<true ><<<dim3(n4/256), 256, 0, stream>>>(wq, wqk_hi,      wqk_lo,      n4);
    wsplit_kernel<true ><<<dim3(n4/256), 256, 0, stream>>>(wk, wqk_hi + M1, wqk_lo + M1, n4);
    wsplit_kernel<false><<<dim3(n4/256), 256, 0, stream>>>(wv, wv_hi, nullptr, n4);
    wsplit_kernel<false><<<dim3(n4/256), 256, 0, stream>>>(wo, wo_hi, nullptr, n4);

    // 2. LayerNorm + split
    ln_kernel<<<ROWS, 256, 0, stream>>>(x, ln_w, h_hi, h_lo);

    // 3. [Q|K] = h @ [wq;wk]^T  (split-3, hi/lo out), grid 64x16 = 1024 blocks
    gemm3<3,1><<<dim3(ROWS/128, 2*Dn/128), 256, 0, stream>>>(
        h_hi, h_lo, Dn, 0, wqk_hi, wqk_lo, Dn, 0,
        nullptr, qk_hi, qk_lo, 2*Dn, 0, Dn);

    // 4. V = h @ wv^T, stored transposed per batch vt[b][d][s] (plain bf16), 512 blocks
    gemm3<1,2><<<dim3(Sn/128, Dn/128, Bn), 256, 0, stream>>>(
        h_hi, nullptr, Dn, (long long)Sn * Dn, wv_hi, nullptr, Dn, 0,
        nullptr, vt, nullptr, Sn, (long long)Dn * Sn, Dn);

    // 5. scores = q @ k^T (split-3, f32), all batches: grid 16x16x4 = 1024 blocks
    gemm3<3,0><<<dim3(Sn/128, Sn/128, Bn), 256, 0, stream>>>(
        qk_hi, qk_lo, 2*Dn, (long long)Sn * 2*Dn,
        qk_hi + Dn, qk_lo + Dn, 2*Dn, (long long)Sn * 2*Dn,
        scores, nullptr, nullptr, Sn, (long long)Sn * Sn, Dn);

    // 6. softmax rows -> plain bf16 P in place (row stride 4096 bf16)
    softmax_kernel<<<ROWS, 256, 0, stream>>>(scores);

    // 7. ctx = P @ vt  (bf16 x bf16), grid 16x8x4 = 512 blocks
    gemm3<1,3><<<dim3(Sn/128, Dn/128, Bn), 256, 0, stream>>>(
        (const bf16*)scores, nullptr, 2*Sn, (long long)Sn * 2*Sn,
        vt, nullptr, Sn, (long long)Dn * Sn,
        nullptr, ctx, nullptr, Dn, (long long)Sn * Dn, Sn);

    // 8. out = ctx @ wo^T  (f32 -> d_out), grid 64x8 = 512 blocks
    gemm3<1,0><<<dim3(ROWS/128, Dn/128), 256, 0, stream>>>(
        ctx, nullptr, Dn, 0, wo_hi, nullptr, Dn, 0,
        out, nullptr, nullptr, Dn, 0, Dn);
}

// Round 3
// 465.726 us; speedup vs baseline: 1.8412x; 1.0170x over previous
//
#include <hip/hip_runtime.h>
#include <hip/hip_bf16.h>

using bf16 = __hip_bfloat16;
typedef __attribute__((ext_vector_type(8))) short short8;
typedef __attribute__((ext_vector_type(4))) float f32x4;
typedef __attribute__((ext_vector_type(4))) unsigned short us4;

static constexpr int Bn = 4, Sn = 2048, Dn = 1024;
static constexpr int ROWS = Bn * Sn;  // 8192
static constexpr float EPS = 1e-5f;

__device__ __forceinline__ void splitf(float v, bf16& hi, bf16& lo) {
    hi = __float2bfloat16(v);
    lo = __float2bfloat16(v - __bfloat162float(hi));
}

__device__ __forceinline__ void gload_lds16(const void* g, void* l) {
    __builtin_amdgcn_global_load_lds(
        (__attribute__((address_space(1))) void*)(void*)g,
        (__attribute__((address_space(3))) void*)l, 16, 0, 0);
}

// ---------- weight split, B-style planes [hi | hi | lo], row stride 3072 ----------
__global__ __launch_bounds__(256) void wsplit3_kernel(const float* __restrict__ w,
                                                      bf16* __restrict__ out) {
    const int i = blockIdx.x * 256 + threadIdx.x;  // one thread per 4 elems
    const float4 v = reinterpret_cast<const float4*>(w)[i];
    const int row = i >> 8, c = (i & 255) << 2;
    alignas(8) bf16 h[4], l[4];
    splitf(v.x, h[0], l[0]); splitf(v.y, h[1], l[1]);
    splitf(v.z, h[2], l[2]); splitf(v.w, h[3], l[3]);
    bf16* o = out + (size_t)row * 3072 + c;
    *reinterpret_cast<us4*>(o)        = *reinterpret_cast<const us4*>(h);
    *reinterpret_cast<us4*>(o + 1024) = *reinterpret_cast<const us4*>(h);
    *reinterpret_cast<us4*>(o + 2048) = *reinterpret_cast<const us4*>(l);
}

// ---------- weight hi-only split ----------
__global__ __launch_bounds__(256) void wsplit_hi_kernel(const float* __restrict__ w,
                                                        bf16* __restrict__ hi) {
    const int i = blockIdx.x * 256 + threadIdx.x;
    const float4 v = reinterpret_cast<const float4*>(w)[i];
    alignas(8) bf16 h[4];
    bf16 l;
    splitf(v.x, h[0], l); splitf(v.y, h[1], l);
    splitf(v.z, h[2], l); splitf(v.w, h[3], l);
    *reinterpret_cast<us4*>(hi + i * 4) = *reinterpret_cast<const us4*>(h);
}

// ---------- LayerNorm -> h3, A-style planes [hi | lo | hi], row stride 3072 ----------
__global__ __launch_bounds__(256) void ln3_kernel(const float* __restrict__ x,
                                                  const float* __restrict__ w,
                                                  bf16* __restrict__ h3) {
    const int row = blockIdx.x, tid = threadIdx.x;
    const int lane = tid & 63, wave = tid >> 6;
    const float4 v = reinterpret_cast<const float4*>(x + (size_t)row * Dn)[tid];
    float s  = v.x + v.y + v.z + v.w;
    float s2 = v.x*v.x + v.y*v.y + v.z*v.z + v.w*v.w;
    #pragma unroll
    for (int off = 32; off > 0; off >>= 1) {
        s  += __shfl_down(s,  off, 64);
        s2 += __shfl_down(s2, off, 64);
    }
    __shared__ float red[8];
    if (lane == 0) { red[wave] = s; red[4 + wave] = s2; }
    __syncthreads();
    s  = red[0] + red[1] + red[2] + red[3];
    s2 = red[4] + red[5] + red[6] + red[7];
    const float mu  = s * (1.0f / Dn);
    const float var = s2 * (1.0f / Dn) - mu * mu;
    const float rs  = rsqrtf(var + EPS);
    const float4 wv = reinterpret_cast<const float4*>(w)[tid];
    alignas(8) bf16 h[4], l[4];
    splitf((v.x - mu) * rs * wv.x, h[0], l[0]);
    splitf((v.y - mu) * rs * wv.y, h[1], l[1]);
    splitf((v.z - mu) * rs * wv.z, h[2], l[2]);
    splitf((v.w - mu) * rs * wv.w, h[3], l[3]);
    bf16* o = h3 + (size_t)row * 3072 + tid * 4;
    *reinterpret_cast<us4*>(o)        = *reinterpret_cast<const us4*>(h);
    *reinterpret_cast<us4*>(o + 1024) = *reinterpret_cast<const us4*>(l);
    *reinterpret_cast<us4*>(o + 2048) = *reinterpret_cast<const us4*>(h);
}

// ---------- row softmax (2048 wide), writes plain bf16 P in place ----------
__global__ __launch_bounds__(256) void softmax_kernel(float* __restrict__ scores) {
    const int row = blockIdx.x, tid = threadIdx.x;
    const int lane = tid & 63, wave = tid >> 6;
    float* r = scores + (size_t)row * Sn;
    const float4 v0 = reinterpret_cast<const float4*>(r)[tid];
    const float4 v1 = reinterpret_cast<const float4*>(r)[tid + 256];
    float m = fmaxf(fmaxf(fmaxf(v0.x, v0.y), fmaxf(v0.z, v0.w)),
                    fmaxf(fmaxf(v1.x, v1.y), fmaxf(v1.z, v1.w)));
    #pragma unroll
    for (int off = 32; off > 0; off >>= 1) m = fmaxf(m, __shfl_down(m, off, 64));
    __shared__ float red[8];
    if (lane == 0) red[wave] = m;
    __syncthreads();
    m = fmaxf(fmaxf(red[0], red[1]), fmaxf(red[2], red[3]));
    float e[8];
    e[0] = expf(v0.x - m); e[1] = expf(v0.y - m);
    e[2] = expf(v0.z - m); e[3] = expf(v0.w - m);
    e[4] = expf(v1.x - m); e[5] = expf(v1.y - m);
    e[6] = expf(v1.z - m); e[7] = expf(v1.w - m);
    float s = e[0]+e[1]+e[2]+e[3]+e[4]+e[5]+e[6]+e[7];
    #pragma unroll
    for (int off = 32; off > 0; off >>= 1) s += __shfl_down(s, off, 64);
    if (lane == 0) red[4 + wave] = s;
    __syncthreads();
    s = red[4] + red[5] + red[6] + red[7];
    const float inv = 1.0f / s;
    bf16* hi = reinterpret_cast<bf16*>(r);
    #pragma unroll
    for (int j = 0; j < 4; ++j) hi[tid*4 + j]        = __float2bfloat16(e[j] * inv);
    #pragma unroll
    for (int j = 0; j < 4; ++j) hi[1024 + tid*4 + j] = __float2bfloat16(e[4+j] * inv);
}

// ---------- 128x128 plain bf16 GEMM (C = A @ B^T), 4 waves ----------
// SM: 0 = f32 store, 2 = bf16 transposed store, 3 = bf16 store
template <int SM>
__global__ __launch_bounds__(256)
void gemm3(const bf16* __restrict__ A, int lda, long long sA,
           const bf16* __restrict__ B, int ldb, long long sB,
           float* __restrict__ Cf, bf16* __restrict__ Cb,
           int ldc, long long sC, int K) {
    const int tid = threadIdx.x;
    const int lane = tid & 63, wave = tid >> 6;
    const int bm = blockIdx.x, bn = blockIdx.y;
    const long long aBase = (long long)blockIdx.z * sA;
    const long long bBase = (long long)blockIdx.z * sB;
    const long long cBase = (long long)blockIdx.z * sC;

    __shared__ bf16 sAh[128*32];
    __shared__ bf16 sBh[128*32];

    f32x4 acc[4][4];
    #pragma unroll
    for (int i = 0; i < 4; ++i)
        #pragma unroll
        for (int j = 0; j < 4; ++j) acc[i][j] = f32x4{0.f, 0.f, 0.f, 0.f};

    const int wm = wave >> 1, wn = wave & 1;
    const int fr = lane & 15;
    const int kb = (lane >> 4) * 8;

    for (int k0 = 0; k0 < K; k0 += 32) {
        #pragma unroll
        for (int i = 0; i < 2; ++i) {
            const int idx = (i * 4 + wave) * 64 + lane;
            const int row = idx >> 2;
            const int seg = (idx & 3) * 8;
            const int lds_off = (i * 4 + wave) * 512;  // wave-uniform
            gload_lds16(A + aBase + (long long)(bm * 128 + row) * lda + k0 + seg, sAh + lds_off);
            gload_lds16(B + bBase + (long long)(bn * 128 + row) * ldb + k0 + seg, sBh + lds_off);
        }
        __syncthreads();
        short8 ah[4], bh[4];
        #pragma unroll
        for (int t = 0; t < 4; ++t) {
            ah[t] = *reinterpret_cast<const short8*>(sAh + (wm*64 + t*16 + fr) * 32 + kb);
            bh[t] = *reinterpret_cast<const short8*>(sBh + (wn*64 + t*16 + fr) * 32 + kb);
        }
        #pragma unroll
        for (int mi = 0; mi < 4; ++mi)
            #pragma unroll
            for (int ni = 0; ni < 4; ++ni)
                acc[mi][ni] = __builtin_amdgcn_mfma_f32_16x16x32_bf16(ah[mi], bh[ni], acc[mi][ni], 0, 0, 0);
        __syncthreads();
    }

    #pragma unroll
    for (int mi = 0; mi < 4; ++mi) {
        const int row0 = bm * 128 + wm * 64 + mi * 16 + (lane >> 4) * 4;
        #pragma unroll
        for (int ni = 0; ni < 4; ++ni) {
            const int col = bn * 128 + wn * 64 + ni * 16 + fr;
            if constexpr (SM == 0) {
                #pragma unroll
                for (int r = 0; r < 4; ++r)
                    Cf[cBase + (long long)(row0 + r) * ldc + col] = acc[mi][ni][r];
            } else if constexpr (SM == 2) {
                alignas(8) bf16 th[4];
                #pragma unroll
                for (int r = 0; r < 4; ++r) th[r] = __float2bfloat16(acc[mi][ni][r]);
                const long long o = cBase + (long long)col * ldc + row0;
                *reinterpret_cast<us4*>(Cb + o) = *reinterpret_cast<const us4*>(th);
            } else {
                #pragma unroll
                for (int r = 0; r < 4; ++r)
                    Cb[cBase + (long long)(row0 + r) * ldc + col] = __float2bfloat16(acc[mi][ni][r]);
            }
        }
    }
}

// ---------- 256x256 pipelined bf16 GEMM (C = A @ B^T), 8 waves ----------
// Triple-buffered LDS, prefetch distance 2 K-tiles, counted vmcnt(4),
// XOR chunk swizzle, setprio around MFMA clusters.
// SM: 0 = f32 store, 4 = f32 accumulate, 1 = QK split-plane write (q2/k2)
template <int SM>
__global__ __launch_bounds__(512, 2)
void gemm8(const bf16* __restrict__ A, int lda, long long sA,
           const bf16* __restrict__ B, int ldb, long long sB,
           float* __restrict__ Cf, bf16* __restrict__ Cq, bf16* __restrict__ Ck,
           int ldc, long long sC, int K) {
    const int tid = threadIdx.x;
    const int lane = tid & 63, wave = tid >> 6;
    const int wm = wave >> 2, wn = wave & 3;
    const int fl = lane & 15, s0 = lane >> 4;
    const int bm = blockIdx.x, bn = blockIdx.y;

    __shared__ bf16 lds[3 * 16384];  // 3 x (A 16KB | B 16KB) = 96 KiB

    // stage-side: thread t loads row tr (within 128-half), pre-swizzled chunk sg
    const int tr = tid >> 2;
    const int sg = (tid & 3) ^ ((tr >> 1) & 3);
    const bf16* gA = A + (long long)blockIdx.z * sA + (long long)(bm*256 + tr) * lda + sg*8;
    const bf16* gB = B + (long long)blockIdx.z * sB + (long long)(bn*256 + tr) * ldb + sg*8;
    bf16* ldsw = lds + wave * 512;  // wave-uniform dest base (+lane*8 implicit)
    const long long a128 = (long long)128 * lda, b128 = (long long)128 * ldb;

    // read-side: swizzled chunk per lane (independent of mi since 8%4==0)
    const int sw = (s0 ^ ((fl >> 1) & 3)) * 8;
    const int aoff = (wm*128 + fl) * 32 + sw;
    const int boff = 8192 + (wn*64 + fl) * 32 + sw;

    f32x4 acc[8][4];
    #pragma unroll
    for (int i = 0; i < 8; ++i)
        #pragma unroll
        for (int j = 0; j < 4; ++j) acc[i][j] = f32x4{0.f, 0.f, 0.f, 0.f};

    const int NT = K >> 5;
    // prologue: stage tile0 -> buf0, tile1 -> buf1 (8 loads), wait tile0
    gload_lds16(gA,             ldsw);
    gload_lds16(gA + a128,      ldsw + 4096);
    gload_lds16(gB,             ldsw + 8192);
    gload_lds16(gB + b128,      ldsw + 12288);
    gload_lds16(gA + 32,        ldsw + 16384);
    gload_lds16(gA + a128 + 32, ldsw + 16384 + 4096);
    gload_lds16(gB + 32,        ldsw + 16384 + 8192);
    gload_lds16(gB + b128 + 32, ldsw + 16384 + 12288);
    asm volatile("s_waitcnt vmcnt(4)" ::: "memory");
    __builtin_amdgcn_s_barrier();

    int c0 = 0;
    for (int kt = 0; kt < NT; ++kt) {
        const int c2 = (c0 >= 1) ? c0 - 1 : 2;  // (c0+2)%3
        int ktp = kt + 2; if (ktp >= NT) ktp = 0;  // harmless overfetch at tail
        const int kp = ktp << 5;
        const bf16* ab = lds + c0 * 16384;
        bf16* pw = ldsw + c2 * 16384;

        // phase 0: stage A halves of tile ktp; read B n0-3, A m0-3; 16 MFMA
        gload_lds16(gA + kp,        pw);
        gload_lds16(gA + kp + a128, pw + 4096);
        short8 bfr[4], afr[4];
        #pragma unroll
        for (int ni = 0; ni < 4; ++ni) bfr[ni] = *reinterpret_cast<const short8*>(ab + boff + ni*512);
        #pragma unroll
        for (int mi = 0; mi < 4; ++mi) afr[mi] = *reinterpret_cast<const short8*>(ab + aoff + mi*512);
        __builtin_amdgcn_s_barrier();
        __builtin_amdgcn_s_setprio(1);
        #pragma unroll
        for (int mi = 0; mi < 4; ++mi)
            #pragma unroll
            for (int ni = 0; ni < 4; ++ni)
                acc[mi][ni] = __builtin_amdgcn_mfma_f32_16x16x32_bf16(afr[mi], bfr[ni], acc[mi][ni], 0, 0, 0);
        __builtin_amdgcn_s_setprio(0);
        __builtin_amdgcn_s_barrier();

        // phase 1: stage B halves of tile ktp; read A m4-7; 16 MFMA
        gload_lds16(gB + kp,        pw + 8192);
        gload_lds16(gB + kp + b128, pw + 12288);
        short8 af2[4];
        #pragma unroll
        for (int mi = 0; mi < 4; ++mi) af2[mi] = *reinterpret_cast<const short8*>(ab + aoff + (mi+4)*512);
        __builtin_amdgcn_s_barrier();
        __builtin_amdgcn_s_setprio(1);
        #pragma unroll
        for (int mi = 0; mi < 4; ++mi)
            #pragma unroll
            for (int ni = 0; ni < 4; ++ni)
                acc[mi+4][ni] = __builtin_amdgcn_mfma_f32_16x16x32_bf16(af2[mi], bfr[ni], acc[mi+4][ni], 0, 0, 0);
        __builtin_amdgcn_s_setprio(0);
        // tile kt+1 landed (oldest 4); tile kt+2's 4 stay in flight
        asm volatile("s_waitcnt vmcnt(4)" ::: "memory");
        __builtin_amdgcn_s_barrier();
        c0 = (c0 < 2) ? c0 + 1 : 0;
    }

    const long long cB = (long long)blockIdx.z * sC;
    #pragma unroll
    for (int mi = 0; mi < 8; ++mi) {
        const int row0 = bm*256 + wm*128 + mi*16 + s0*4;
        #pragma unroll
        for (int ni = 0; ni < 4; ++ni) {
            const int col = bn*256 + wn*64 + ni*16 + fl;
            if constexpr (SM == 0) {
                #pragma unroll
                for (int r = 0; r < 4; ++r)
                    Cf[cB + (long long)(row0 + r) * ldc + col] = acc[mi][ni][r];
            } else if constexpr (SM == 4) {
                #pragma unroll
                for (int r = 0; r < 4; ++r) {
                    const long long o = cB + (long long)(row0 + r) * ldc + col;
                    Cf[o] += acc[mi][ni][r];
                }
            } else {  // SM == 1: QK split-plane write; ldc = physical row stride (2048)
                if (col < 1024) {  // q: planes [lo | hi]
                    #pragma unroll
                    for (int r = 0; r < 4; ++r) {
                        bf16 h, l; splitf(acc[mi][ni][r], h, l);
                        const long long o = (long long)(row0 + r) * ldc + col;
                        Cq[o] = l; Cq[o + 1024] = h;
                    }
                } else {  // k: planes [hi | lo]
                    const int c = col - 1024;
                    #pragma unroll
                    for (int r = 0; r < 4; ++r) {
                        bf16 h, l; splitf(acc[mi][ni][r], h, l);
                        const long long o = (long long)(row0 + r) * ldc + c;
                        Ck[o] = h; Ck[o + 1024] = l;
                    }
                }
            }
        }
    }
}

extern "C" void kernel_launch(void* const* d_in, const int* in_sizes, int n_in,
                              void* d_out, int out_size, void* d_ws, size_t ws_size,
                              hipStream_t stream) {
    const float* x    = (const float*)d_in[0];
    const float* ln_w = (const float*)d_in[1];
    const float* wq   = (const float*)d_in[2];
    const float* wk   = (const float*)d_in[3];
    const float* wv   = (const float*)d_in[4];
    const float* wo   = (const float*)d_in[5];
    float* out = (float*)d_out;

    const size_t M1 = 1u << 20;
    bf16* base = (bf16*)d_ws;  // total ws use: 144 MiB
    // region A [0, 32M elems = 64MB): transient, dead after V GEMM; then f32 scores
    bf16* h3    = base;              // 24M elems: [8192][3072] planes (hi|lo|hi)
    bf16* wqk3  = base + 24*M1;      // 6M: [2048][3072] planes (hi|hi|lo), wq rows 0..1023
    bf16* wv_hi = base + 30*M1;      // 1M
    float* scores = (float*)base;    // 16M f32, overlays region A
    // persistent
    bf16* q2    = base + 32*M1;      // 16M: [8192][2048] planes (lo|hi); dead after scores
    bf16* k2    = base + 48*M1;      // 16M: [8192][2048] planes (hi|lo)
    bf16* vt    = base + 64*M1;      // 8M: [4][1024][2048]
    bf16* ctx   = base + 32*M1;      // 8M, overlays dead q2
    bf16* wo_hi = base + 40*M1;      // 1M, overlays dead q2 tail

    // 1. weight splits (wo split deferred until q2 is dead)
    wsplit3_kernel<<<dim3(1024), 256, 0, stream>>>(wq, wqk3);
    wsplit3_kernel<<<dim3(1024), 256, 0, stream>>>(wk, wqk3 + (size_t)1024 * 3072);
    wsplit_hi_kernel<<<dim3(1024), 256, 0, stream>>>(wv, wv_hi);

    // 2. LayerNorm -> h3 planes
    ln3_kernel<<<ROWS, 256, 0, stream>>>(x, ln_w, h3);

    // 3. [Q|K] = h @ [wq;wk]^T, exact split-3 via planes, K'=3072. grid 32x8=256
    gemm8<1><<<dim3(ROWS/256, 2*Dn/256), 512, 0, stream>>>(
        h3, 3072, 0, wqk3, 3072, 0,
        nullptr, q2, k2, 2048, 0, 3072);

    // 4. V = h @ wv^T (hi-only), transposed store vt[b][d][s]. grid 16x8x4=512
    gemm3<2><<<dim3(Sn/128, Dn/128, Bn), 256, 0, stream>>>(
        h3, 3072, (long long)Sn * 3072, wv_hi, 1024, 0,
        nullptr, vt, Sn, (long long)Dn * Sn, 1024);

    // 5a. scores = qlo@khi^T + qhi@klo^T (cross terms, K'=2048). grid 8x8x4=256
    gemm8<0><<<dim3(Sn/256, Sn/256, Bn), 512, 0, stream>>>(
        q2, 2048, (long long)Sn * 2048, k2, 2048, (long long)Sn * 2048,
        scores, nullptr, nullptr, Sn, (long long)Sn * Sn, 2048);
    // 5b. scores += qhi@khi^T (K'=1024, accumulate)
    gemm8<4><<<dim3(Sn/256, Sn/256, Bn), 512, 0, stream>>>(
        q2 + 1024, 2048, (long long)Sn * 2048, k2, 2048, (long long)Sn * 2048,
        scores, nullptr, nullptr, Sn, (long long)Sn * Sn, 1024);

    // 6. softmax rows -> plain bf16 P in place (row stride 4096 bf16)
    softmax_kernel<<<ROWS, 256, 0, stream>>>(scores);

    // 7. wo split (q2 region now dead)
    wsplit_hi_kernel<<<dim3(1024), 256, 0, stream>>>(wo, wo_hi);

    // 8. ctx = P @ vt. grid 16x8x4=512
    gemm3<3><<<dim3(Sn/128, Dn/128, Bn), 256, 0, stream>>>(
        (const bf16*)scores, 2*Sn, (long long)Sn * 2*Sn,
        vt, Sn, (long long)Dn * Sn,
        nullptr, ctx, Dn, (long long)Sn * Dn, Sn);

    // 9. out = ctx @ wo^T (f32 -> d_out). grid 64x8=512
    gemm3<0><<<dim3(ROWS/128, Dn/128), 256, 0, stream>>>(
        ctx, Dn, 0, wo_hi, Dn, 0,
        out, nullptr, Dn, 0, Dn);
}

// Round 7
// 436.516 us; speedup vs baseline: 1.9644x; 1.0669x over previous
//
#include <hip/hip_runtime.h>
#include <hip/hip_bf16.h>

using bf16 = __hip_bfloat16;
typedef __attribute__((ext_vector_type(8))) short short8;
typedef __attribute__((ext_vector_type(4))) float f32x4;
typedef __attribute__((ext_vector_type(4))) unsigned short us4;

static constexpr int Bn = 4, Sn = 2048, Dn = 1024;
static constexpr int ROWS = Bn * Sn;  // 8192
static constexpr float EPS = 1e-5f;

__device__ __forceinline__ void splitf(float v, bf16& hi, bf16& lo) {
    hi = __float2bfloat16(v);
    lo = __float2bfloat16(v - __bfloat162float(hi));
}

__device__ __forceinline__ void gload_lds16(const void* g, void* l) {
    __builtin_amdgcn_global_load_lds(
        (__attribute__((address_space(1))) void*)(void*)g,
        (__attribute__((address_space(3))) void*)l, 16, 0, 0);
}

// ---------- weight split -> [hi | lo] planes, row stride 2048 ----------
__global__ __launch_bounds__(256) void wsplit2_kernel(const float* __restrict__ w,
                                                      bf16* __restrict__ out) {
    const int i = blockIdx.x * 256 + threadIdx.x;  // one thread per 4 elems
    const float4 v = reinterpret_cast<const float4*>(w)[i];
    const int row = i >> 8, c = (i & 255) << 2;
    alignas(8) bf16 h[4], l[4];
    splitf(v.x, h[0], l[0]); splitf(v.y, h[1], l[1]);
    splitf(v.z, h[2], l[2]); splitf(v.w, h[3], l[3]);
    bf16* o = out + (size_t)row * 2048 + c;
    *reinterpret_cast<us4*>(o)        = *reinterpret_cast<const us4*>(h);
    *reinterpret_cast<us4*>(o + 1024) = *reinterpret_cast<const us4*>(l);
}

// ---------- weight hi-only split ----------
__global__ __launch_bounds__(256) void wsplit_hi_kernel(const float* __restrict__ w,
                                                        bf16* __restrict__ hi) {
    const int i = blockIdx.x * 256 + threadIdx.x;
    const float4 v = reinterpret_cast<const float4*>(w)[i];
    alignas(8) bf16 h[4];
    bf16 l;
    splitf(v.x, h[0], l); splitf(v.y, h[1], l);
    splitf(v.z, h[2], l); splitf(v.w, h[3], l);
    *reinterpret_cast<us4*>(hi + i * 4) = *reinterpret_cast<const us4*>(h);
}

// ---------- LayerNorm -> h2 [hi | lo] planes, row stride 2048 ----------
__global__ __launch_bounds__(256) void ln2_kernel(const float* __restrict__ x,
                                                  const float* __restrict__ w,
                                                  bf16* __restrict__ h2) {
    const int row = blockIdx.x, tid = threadIdx.x;
    const int lane = tid & 63, wave = tid >> 6;
    const float4 v = reinterpret_cast<const float4*>(x + (size_t)row * Dn)[tid];
    float s  = v.x + v.y + v.z + v.w;
    float s2 = v.x*v.x + v.y*v.y + v.z*v.z + v.w*v.w;
    #pragma unroll
    for (int off = 32; off > 0; off >>= 1) {
        s  += __shfl_down(s,  off, 64);
        s2 += __shfl_down(s2, off, 64);
    }
    __shared__ float red[8];
    if (lane == 0) { red[wave] = s; red[4 + wave] = s2; }
    __syncthreads();
    s  = red[0] + red[1] + red[2] + red[3];
    s2 = red[4] + red[5] + red[6] + red[7];
    const float mu  = s * (1.0f / Dn);
    const float var = s2 * (1.0f / Dn) - mu * mu;
    const float rs  = rsqrtf(var + EPS);
    const float4 wv = reinterpret_cast<const float4*>(w)[tid];
    alignas(8) bf16 h[4], l[4];
    splitf((v.x - mu) * rs * wv.x, h[0], l[0]);
    splitf((v.y - mu) * rs * wv.y, h[1], l[1]);
    splitf((v.z - mu) * rs * wv.z, h[2], l[2]);
    splitf((v.w - mu) * rs * wv.w, h[3], l[3]);
    bf16* o = h2 + (size_t)row * 2048 + tid * 4;
    *reinterpret_cast<us4*>(o)        = *reinterpret_cast<const us4*>(h);
    *reinterpret_cast<us4*>(o + 1024) = *reinterpret_cast<const us4*>(l);
}

// ---------- row softmax (2048 wide), writes plain bf16 P in place ----------
__global__ __launch_bounds__(256) void softmax_kernel(float* __restrict__ scores) {
    const int row = blockIdx.x, tid = threadIdx.x;
    const int lane = tid & 63, wave = tid >> 6;
    float* r = scores + (size_t)row * Sn;
    const float4 v0 = reinterpret_cast<const float4*>(r)[tid];
    const float4 v1 = reinterpret_cast<const float4*>(r)[tid + 256];
    float m = fmaxf(fmaxf(fmaxf(v0.x, v0.y), fmaxf(v0.z, v0.w)),
                    fmaxf(fmaxf(v1.x, v1.y), fmaxf(v1.z, v1.w)));
    #pragma unroll
    for (int off = 32; off > 0; off >>= 1) m = fmaxf(m, __shfl_down(m, off, 64));
    __shared__ float red[8];
    if (lane == 0) red[wave] = m;
    __syncthreads();
    m = fmaxf(fmaxf(red[0], red[1]), fmaxf(red[2], red[3]));
    float e[8];
    e[0] = expf(v0.x - m); e[1] = expf(v0.y - m);
    e[2] = expf(v0.z - m); e[3] = expf(v0.w - m);
    e[4] = expf(v1.x - m); e[5] = expf(v1.y - m);
    e[6] = expf(v1.z - m); e[7] = expf(v1.w - m);
    float s = e[0]+e[1]+e[2]+e[3]+e[4]+e[5]+e[6]+e[7];
    #pragma unroll
    for (int off = 32; off > 0; off >>= 1) s += __shfl_down(s, off, 64);
    if (lane == 0) red[4 + wave] = s;
    __syncthreads();
    s = red[4] + red[5] + red[6] + red[7];
    const float inv = 1.0f / s;
    bf16* hi = reinterpret_cast<bf16*>(r);
    #pragma unroll
    for (int j = 0; j < 4; ++j) hi[tid*4 + j]        = __float2bfloat16(e[j] * inv);
    #pragma unroll
    for (int j = 0; j < 4; ++j) hi[1024 + tid*4 + j] = __float2bfloat16(e[4+j] * inv);
}

// ---------- 128x128 plain bf16 GEMM (C = A @ B^T), 4 waves ----------
// SM: 0 = f32 store, 2 = bf16 transposed store, 3 = bf16 store
template <int SM>
__global__ __launch_bounds__(256)
void gemm3(const bf16* __restrict__ A, int lda, long long sA,
           const bf16* __restrict__ B, int ldb, long long sB,
           float* __restrict__ Cf, bf16* __restrict__ Cb,
           int ldc, long long sC, int K) {
    const int tid = threadIdx.x;
    const int lane = tid & 63, wave = tid >> 6;
    const int bm = blockIdx.x, bn = blockIdx.y;
    const long long aBase = (long long)blockIdx.z * sA;
    const long long bBase = (long long)blockIdx.z * sB;
    const long long cBase = (long long)blockIdx.z * sC;

    __shared__ bf16 sAh[128*32];
    __shared__ bf16 sBh[128*32];

    f32x4 acc[4][4];
    #pragma unroll
    for (int i = 0; i < 4; ++i)
        #pragma unroll
        for (int j = 0; j < 4; ++j) acc[i][j] = f32x4{0.f, 0.f, 0.f, 0.f};

    const int wm = wave >> 1, wn = wave & 1;
    const int fr = lane & 15;
    const int kb = (lane >> 4) * 8;

    for (int k0 = 0; k0 < K; k0 += 32) {
        #pragma unroll
        for (int i = 0; i < 2; ++i) {
            const int idx = (i * 4 + wave) * 64 + lane;
            const int row = idx >> 2;
            const int seg = (idx & 3) * 8;
            const int lds_off = (i * 4 + wave) * 512;  // wave-uniform
            gload_lds16(A + aBase + (long long)(bm * 128 + row) * lda + k0 + seg, sAh + lds_off);
            gload_lds16(B + bBase + (long long)(bn * 128 + row) * ldb + k0 + seg, sBh + lds_off);
        }
        __syncthreads();
        short8 ah[4], bh[4];
        #pragma unroll
        for (int t = 0; t < 4; ++t) {
            ah[t] = *reinterpret_cast<const short8*>(sAh + (wm*64 + t*16 + fr) * 32 + kb);
            bh[t] = *reinterpret_cast<const short8*>(sBh + (wn*64 + t*16 + fr) * 32 + kb);
        }
        #pragma unroll
        for (int mi = 0; mi < 4; ++mi)
            #pragma unroll
            for (int ni = 0; ni < 4; ++ni)
                acc[mi][ni] = __builtin_amdgcn_mfma_f32_16x16x32_bf16(ah[mi], bh[ni], acc[mi][ni], 0, 0, 0);
        __syncthreads();
    }

    #pragma unroll
    for (int mi = 0; mi < 4; ++mi) {
        const int row0 = bm * 128 + wm * 64 + mi * 16 + (lane >> 4) * 4;
        #pragma unroll
        for (int ni = 0; ni < 4; ++ni) {
            const int col = bn * 128 + wn * 64 + ni * 16 + fr;
            if constexpr (SM == 0) {
                #pragma unroll
                for (int r = 0; r < 4; ++r)
                    Cf[cBase + (long long)(row0 + r) * ldc + col] = acc[mi][ni][r];
            } else if constexpr (SM == 2) {
                alignas(8) bf16 th[4];
                #pragma unroll
                for (int r = 0; r < 4; ++r) th[r] = __float2bfloat16(acc[mi][ni][r]);
                const long long o = cBase + (long long)col * ldc + row0;
                *reinterpret_cast<us4*>(Cb + o) = *reinterpret_cast<const us4*>(th);
            } else {
                #pragma unroll
                for (int r = 0; r < 4; ++r)
                    Cb[cBase + (long long)(row0 + r) * ldc + col] = __float2bfloat16(acc[mi][ni][r]);
            }
        }
    }
}

// ---------- 256x256 8-phase split-3 GEMM, K'=3072 over 2-plane storage ----------
// A physical [M][2048] = [Ahi|Alo]; B physical [N][2048] = [Bhi|Blo].
// Logical K = 3072 in three 1024-groups; group g uses A-plane (RA>>g)&1, B-plane (RB>>g)&1.
// SM: 0 = f32 store; 1 = QK epilogue -> q2/k2 [hi|lo] planes.
// 8 waves (2Mx4N), per-wave C 128x64. LDS: 8 slots of 16KB: slot(buf,mat,ks) = 256 rows x 32 k.
// Swizzle: 16B-chunk ^= ((row>>1)&3) — measured 0 bank conflicts (round 3).
#define G256_PHASE(BUF, KS, MG, READB, ST_T, ST_MAT, ST_KS, VM)                              \
    {                                                                                        \
        const int slotA_ = (((BUF) * 2 + 0) * 2 + (KS)) * 8192;                              \
        const int slotB_ = (((BUF) * 2 + 1) * 2 + (KS)) * 8192;                              \
        if (READB) {                                                                         \
            _Pragma("unroll")                                                                \
            for (int n = 0; n < 4; ++n)                                                      \
                bfr[n] = *reinterpret_cast<const short8*>(lds + slotB_ + boff + n * 512);    \
        }                                                                                    \
        short8 afr[4];                                                                       \
        _Pragma("unroll")                                                                    \
        for (int m = 0; m < 4; ++m)                                                          \
            afr[m] = *reinterpret_cast<const short8*>(lds + slotA_ + aoff + ((MG)*4 + m) * 512); \
        {   /* stage one half-tile (2 x gload_lds) */                                        \
            const int tc_ = ((ST_T) < 47) ? (ST_T) : 47;                                     \
            const int slot_ = ((((ST_T) & 1) * 2 + (ST_MAT)) * 2 + (ST_KS)) * 8192;          \
            const int R_ = (ST_MAT) ? RB : RA;                                               \
            const int kb_ = (((R_ >> (tc_ >> 4)) & 1) << 10) + ((tc_ & 15) << 6) + ((ST_KS) << 5); \
            const bf16* g_ = (ST_MAT) ? gB : gA;                                             \
            const int ld_ = (ST_MAT) ? ldb : lda;                                            \
            gload_lds16(g_ + (long long)srow * ld_ + kb_ + schunk, lds + slot_ + wave * 512);\
            gload_lds16(g_ + (long long)(128 + srow) * ld_ + kb_ + schunk,                   \
                        lds + slot_ + 4096 + wave * 512);                                    \
        }                                                                                    \
        __builtin_amdgcn_s_barrier();                                                        \
        asm volatile("s_waitcnt lgkmcnt(0)" ::: "memory");                                   \
        __builtin_amdgcn_sched_barrier(0);                                                   \
        __builtin_amdgcn_s_setprio(1);                                                       \
        _Pragma("unroll")                                                                    \
        for (int m = 0; m < 4; ++m)                                                          \
            _Pragma("unroll")                                                                \
            for (int n = 0; n < 4; ++n)                                                      \
                acc[(MG)*4 + m][n] = __builtin_amdgcn_mfma_f32_16x16x32_bf16(                \
                    afr[m], bfr[n], acc[(MG)*4 + m][n], 0, 0, 0);                            \
        __builtin_amdgcn_s_setprio(0);                                                       \
        if (VM) asm volatile("s_waitcnt vmcnt(4)" ::: "memory");                             \
        __builtin_amdgcn_s_barrier();                                                        \
    }

template <int RA, int RB, int SM>
__global__ __launch_bounds__(512, 2)
void gemm256(const bf16* __restrict__ A, int lda, long long sA,
             const bf16* __restrict__ B, int ldb, long long sB,
             float* __restrict__ Cf, bf16* __restrict__ Cq, bf16* __restrict__ Ck,
             int ldc, long long sC) {
    const int tid = threadIdx.x;
    const int lane = tid & 63, wave = tid >> 6;
    const int wm = wave >> 2, wn = wave & 3;
    const int fr = lane & 15, s0 = lane >> 4;
    const int bm = blockIdx.x, bn = blockIdx.y;

    __shared__ bf16 lds[8 * 8192];  // 128 KiB

    const bf16* gA = A + (long long)blockIdx.z * sA + (long long)(bm * 256) * lda;
    const bf16* gB = B + (long long)blockIdx.z * sB + (long long)(bn * 256) * ldb;

    // staging: call c covers rows c*128..c*128+127; 4 threads per 64B row
    const int srow = tid >> 2;
    const int schunk = (((tid & 3) ^ ((tid >> 3) & 3))) * 8;  // pre-swizzled source chunk

    // read-side fragment offsets (elems); swizzled chunk = s0 ^ ((row>>1)&3)
    const int rsw = (s0 ^ ((fr >> 1) & 3)) * 8;
    const int aoff = (wm * 128 + fr) * 32 + rsw;
    const int boff = (wn * 64 + fr) * 32 + rsw;

    f32x4 acc[8][4];
    #pragma unroll
    for (int i = 0; i < 8; ++i)
        #pragma unroll
        for (int j = 0; j < 4; ++j) acc[i][j] = f32x4{0.f, 0.f, 0.f, 0.f};
    short8 bfr[4];

    // prologue: stage t0 fully + t1 k0-halves, wait for t0 (oldest 8 of 12)
    {
        #pragma unroll
        for (int st = 0; st < 6; ++st) {
            const int t_ = (st < 4) ? 0 : 1;
            const int mat_ = st & 1;
            const int ks_ = (st < 4) ? (st >> 1) : 0;
            const int slot_ = (((t_ & 1) * 2 + mat_) * 2 + ks_) * 8192;
            const int R_ = mat_ ? RB : RA;
            const int kb_ = (((R_ >> (t_ >> 4)) & 1) << 10) + ((t_ & 15) << 6) + (ks_ << 5);
            const bf16* g_ = mat_ ? gB : gA;
            const int ld_ = mat_ ? ldb : lda;
            gload_lds16(g_ + (long long)srow * ld_ + kb_ + schunk, lds + slot_ + wave * 512);
            gload_lds16(g_ + (long long)(128 + srow) * ld_ + kb_ + schunk,
                        lds + slot_ + 4096 + wave * 512);
        }
        asm volatile("s_waitcnt vmcnt(4)" ::: "memory");
        __builtin_amdgcn_s_barrier();
    }

    for (int j = 0; j < 24; ++j) {
        const int t0 = 2 * j, t1 = 2 * j + 1;
        G256_PHASE(0, 0, 0, true,  t1,     0, 1, false)
        G256_PHASE(0, 0, 1, false, t1,     1, 1, false)
        G256_PHASE(0, 1, 0, true,  t0 + 2, 0, 0, false)
        G256_PHASE(0, 1, 1, false, t0 + 2, 1, 0, true)
        G256_PHASE(1, 0, 0, true,  t0 + 2, 0, 1, false)
        G256_PHASE(1, 0, 1, false, t0 + 2, 1, 1, false)
        G256_PHASE(1, 1, 0, true,  t1 + 2, 0, 0, false)
        G256_PHASE(1, 1, 1, false, t1 + 2, 1, 0, true)
    }

    const long long cB = (long long)blockIdx.z * sC;
    #pragma unroll
    for (int mi = 0; mi < 8; ++mi) {
        const int row0 = bm * 256 + wm * 128 + mi * 16 + s0 * 4;
        #pragma unroll
        for (int ni = 0; ni < 4; ++ni) {
            const int col = bn * 256 + wn * 64 + ni * 16 + fr;
            if constexpr (SM == 0) {
                #pragma unroll
                for (int r = 0; r < 4; ++r)
                    Cf[cB + (long long)(row0 + r) * ldc + col] = acc[mi][ni][r];
            } else {  // QK epilogue: cols 0-1023 -> q2 [hi|lo], 1024-2047 -> k2 [hi|lo]
                #pragma unroll
                for (int r = 0; r < 4; ++r) {
                    bf16 h, l; splitf(acc[mi][ni][r], h, l);
                    bf16* dst = (col < 1024) ? Cq : Ck;
                    const int c = col & 1023;
                    const long long o = (long long)(row0 + r) * 2048 + c;
                    dst[o] = h; dst[o + 1024] = l;
                }
            }
        }
    }
}

extern "C" void kernel_launch(void* const* d_in, const int* in_sizes, int n_in,
                              void* d_out, int out_size, void* d_ws, size_t ws_size,
                              hipStream_t stream) {
    const float* x    = (const float*)d_in[0];
    const float* ln_w = (const float*)d_in[1];
    const float* wq   = (const float*)d_in[2];
    const float* wk   = (const float*)d_in[3];
    const float* wv   = (const float*)d_in[4];
    const float* wo   = (const float*)d_in[5];
    float* out = (float*)d_out;

    const size_t M1 = 1u << 20;
    bf16* base = (bf16*)d_ws;  // total ws use: 162 MiB
    // region A [0, 32M elems): transient (h2/w2/wv_hi), later f32 scores
    bf16* h2    = base;              // 16M elems: [8192][2048] = [hi|lo]
    bf16* w2    = base + 16*M1;      // 4M: [2048][2048] = [hi|lo], wq rows 0-1023, wk 1024-2047
    bf16* wv_hi = base + 20*M1;      // 1M
    float* scores = (float*)base;    // 16M f32 = 64MB, overlays region A
    // persistent
    bf16* q2    = base + 32*M1;      // 16M: [8192][2048] = [qhi|qlo]
    bf16* k2    = base + 48*M1;      // 16M: [8192][2048] = [khi|klo]
    bf16* vt    = base + 64*M1;      // 8M: [4][1024][2048]
    bf16* ctx   = base + 72*M1;      // 8M
    bf16* wo_hi = base + 80*M1;      // 1M

    // 1. weight splits (wo deferred — not needed until after scores)
    wsplit2_kernel<<<dim3(1024), 256, 0, stream>>>(wq, w2);
    wsplit2_kernel<<<dim3(1024), 256, 0, stream>>>(wk, w2 + (size_t)1024 * 2048);
    wsplit_hi_kernel<<<dim3(1024), 256, 0, stream>>>(wv, wv_hi);

    // 2. LayerNorm -> h2 [hi|lo]
    ln2_kernel<<<ROWS, 256, 0, stream>>>(x, ln_w, h2);

    // 3. [Q|K] = h @ [wq;wk]^T, split-3 via plane remap (hh·wh + hl·wh + hh·wl).
    //    A groups (hh,hl,hh) -> RA=0b010; B groups (wh,wh,wl) -> RB=0b100. grid 32x8
    gemm256<0b010, 0b100, 1><<<dim3(ROWS/256, 2*Dn/256), 512, 0, stream>>>(
        h2, 2048, 0, w2, 2048, 0,
        nullptr, q2, k2, 0, 0);

    // 4. V = h @ wv^T (hi-only), transposed store vt[b][d][s]. grid 16x8x4
    gemm3<2><<<dim3(Sn/128, Dn/128, Bn), 256, 0, stream>>>(
        h2, 2048, (long long)Sn * 2048, wv_hi, 1024, 0,
        nullptr, vt, Sn, (long long)Dn * Sn, 1024);

    // 5. scores = q @ k^T, split-3 (qh·kh + qh·kl + ql·kh).
    //    A groups (qh,qh,ql) -> RA=0b100; B groups (kh,kl,kh) -> RB=0b010. grid 8x8x4
    gemm256<0b100, 0b010, 0><<<dim3(Sn/256, Sn/256, Bn), 512, 0, stream>>>(
        q2, 2048, (long long)Sn * 2048, k2, 2048, (long long)Sn * 2048,
        scores, nullptr, nullptr, Sn, (long long)Sn * Sn);

    // 6. softmax rows -> plain bf16 P in place (row stride 4096 bf16)
    softmax_kernel<<<ROWS, 256, 0, stream>>>(scores);

    // 7. wo split (transient region for it is free now)
    wsplit_hi_kernel<<<dim3(1024), 256, 0, stream>>>(wo, wo_hi);

    // 8. ctx = P @ vt. grid 16x8x4
    gemm3<3><<<dim3(Sn/128, Dn/128, Bn), 256, 0, stream>>>(
        (const bf16*)scores, 2*Sn, (long long)Sn * 2*Sn,
        vt, Sn, (long long)Dn * Sn,
        nullptr, ctx, Dn, (long long)Sn * Dn, Sn);

    // 9. out = ctx @ wo^T (f32 -> d_out). grid 64x8
    gemm3<0><<<dim3(ROWS/128, Dn/128), 256, 0, stream>>>(
        ctx, Dn, 0, wo_hi, Dn, 0,
        out, nullptr, Dn, 0, Dn);
}